// Round 30
// baseline (160.084 us; speedup 1.0000x reference)
//
#include <hip/hip_runtime.h>
#include <cstdint>

#define B 16
#define N 262144
#define PRE 6000
#define KOUT 1000
#define MW 94            // 64-bit mask words per row (6016 bits >= 6000)
#define CW 24            // fast-path chunks: rows 0..1535 — R28-proven margin
                         // (expected keeps in 1536 rows ~1190 >> 1000; the
                         // R29 CW=20 attempt had margin ~3-8% and failed)
#define NTILE 300        // CW*(CW+1)/2 upper-triangle tiles
#define ECAP 4096        // per-image edge-list capacity
#define RMAX 64          // level-round cap before rescue
#define NBIN 2049
#define PREFILT 1967     // prefilter bin: E[keys above] ~9.9k >> 6k (40 sigma)
#define PGATE 0.9599609375f  // = 1966/2048 exactly; s >= PGATE <=> bin >= 1967
#define IMGMAX 511.0f
#define NMS_TH 0.7f

typedef unsigned int u32;
typedef unsigned long long u64;

// ---- workspace layout (bytes) ----
#define OFF_MASK  0ull                    // 16*94*6000*8         = 72,192,000 (rescue only)
#define OFF_SEL   72192000ull             // 16*16384*8           =  2,097,152
#define OFF_BOX   74289152ull             // 16*6016*16           =  1,540,096
#define OFF_VAL   75829248ull             // 16*96*8              =     12,288
#define OFF_HIST  75841536ull             // 16*2052*4            =    131,328
#define OFF_CAB   75972864ull             // 16*2052*4            =    131,328
#define OFF_BCNT  76104192ull             // 16*2052*4            =    131,328
#define OFF_T     76235520ull             // 16*4                 =         64
#define OFF_M     76235584ull             // 16*4                 =         64
#define OFF_FLAG  76235648ull             // 16*4                 =         64
#define OFF_ECNT  76235712ull             // 16*4                 =         64
#define OFF_EDG   76235776ull             // 16*4096*4            =    262,144
#define OFF_DW    76497920ull             // 16*CW*64*8           <=   327,680
#define OFF_PL    76825600ull             // 16*16384*8           =  2,097,152
#define OFF_PCNT  78922752ull             // 16*4                 =         64
#define WS_NEED   78922816ull
// zero region each call: OFF_VAL..OFF_EDG = 406,528 B (25,408 uint4) + pcnt

// Box decode — mirrors reference op order; contraction off so we don't fuse
// mul+add where XLA doesn't (keep/valid comparisons must match bit-for-bit).
__device__ __forceinline__ void box_from(const float4 a, const float4 d,
    float& x1, float& y1, float& x2, float& y2, bool& valid) {
#pragma clang fp contract(off)
  float w  = a.z - a.x;
  float h  = a.w - a.y;
  float cx = a.x + 0.5f * w;
  float cy = a.y + 0.5f * h;
  cx = cx + d.x * w;
  cy = cy + d.y * h;
  w = w * expf(d.z);
  h = h * expf(d.w);
  x1 = cx - 0.5f * w;
  y1 = cy - 0.5f * h;
  x2 = cx + 0.5f * w;
  y2 = cy + 0.5f * h;
  x1 = fminf(fmaxf(x1, 0.0f), IMGMAX);
  y1 = fminf(fmaxf(y1, 0.0f), IMGMAX);
  x2 = fminf(fmaxf(x2, 0.0f), IMGMAX);
  y2 = fminf(fmaxf(y2, 0.0f), IMGMAX);
  valid = ((x2 - x1) >= 16.0f) && ((y2 - y1) >= 16.0f);
}

// IoU > 0.7, bit-exact vs IEEE div, mul-form: d = inter - 0.7*denom
// (fp err <= ~3e-7*denom). |d| > 1e-4*denom -> sign decides (band 300x
// the error, provably agrees with div compare); borderline -> exact div.
__device__ __forceinline__ bool iou_gt(float inter, float denom) {
  float d = inter - NMS_TH * denom;
  if (__builtin_expect(fabsf(d) <= 1e-4f * denom, 0))
    return (inter / denom) > NMS_TH;
  return d > 0.0f;
}

__device__ __forceinline__ int bin_of(u32 u) {
  if (u == 0u) return 0;
  float s = __uint_as_float(u & 0x7FFFFFFFu);
  return 1 + min(2047, (int)(s * 2048.0f));
}

// K0: workspace zeroing (HIP's fill kernel ran this region at ~10 GB/s).
__global__ void __launch_bounds__(256) k_zero(uint4* __restrict__ a,
                                              uint4* __restrict__ b) {
  int i = blockIdx.x * 256 + threadIdx.x;
  if (i < 25408) a[i] = make_uint4(0u, 0u, 0u, 0u);
  if (i < 4)     b[i] = make_uint4(0u, 0u, 0u, 0u);
}

// K1 (LIGHT, TWO-PHASE): phase A scans 8 scores/thread (float4 stream) and
// queues gated indices to LDS; phase B decodes the queue in parallel.
__global__ void k_hist(const float4* __restrict__ anch, const float2* __restrict__ probs,
                       const float4* __restrict__ delt, u32* __restrict__ hist,
                       float4* __restrict__ boxes, u64* __restrict__ plist,
                       u32* __restrict__ pcnt) {
  __shared__ u32 sh[128];                    // bins [1921..2048]
  __shared__ u64 qbuf[192];                  // gated (score,idx)
  __shared__ u64 pbuf[256];                  // valid keys
  __shared__ u32 qcl, pcl, pbase;
  int t = threadIdx.x;
  int img = blockIdx.y;
  if (t == 0) { qcl = 0; pcl = 0; }
  if (blockIdx.x == 0 && t < 16)
    boxes[(size_t)img * 6016 + 6000 + t] = make_float4(0.f, 0.f, 0.f, 0.f);
  if (t < 128) sh[t] = 0;
  __syncthreads();
  const float4* pr4 = (const float4*)(probs + (size_t)img * N);  // 16B-aligned
  int b4 = blockIdx.x * 1024 + t;            // 1024 f4 = 2048 anchors/block
  float4 p0 = pr4[b4];
  float4 p1 = pr4[b4 + 256];
  float4 p2 = pr4[b4 + 512];
  float4 p3 = pr4[b4 + 768];
  auto check = [&](float s, int i) {
    if (s >= PGATE) {                        // exact gate for bin >= PREFILT
      u32 q = atomicAdd(&qcl, 1u);
      if (q < 192u)
        qbuf[q] = ((u64)__float_as_uint(s) << 32) | (u64)(u32)i;
    }
  };
  check(p0.y, 2 * b4);            check(p0.w, 2 * b4 + 1);
  check(p1.y, 2 * (b4 + 256));    check(p1.w, 2 * (b4 + 256) + 1);
  check(p2.y, 2 * (b4 + 512));    check(p2.w, 2 * (b4 + 512) + 1);
  check(p3.y, 2 * (b4 + 768));    check(p3.w, 2 * (b4 + 768) + 1);
  __syncthreads();
  u32 qn = min(qcl, 192u);
  for (u32 q = t; q < qn; q += 256) {        // parallel decode of the queue
    u64 qv = qbuf[q];
    float s = __uint_as_float((u32)(qv >> 32));
    int i = (int)(u32)qv;
    float4 a = anch[i];
    float4 d = delt[(size_t)img * N + i];
    float x1, y1, x2, y2; bool valid;
    box_from(a, d, x1, y1, x2, y2, valid);
    if (valid) {
      int bin = 1 + min(2047, (int)(s * 2048.0f));   // >= PREFILT
      atomicAdd(&sh[bin - 1921], 1u);
      u64 key = ((u64)(__float_as_uint(s) | 0x80000000u) << 32)
              | (u64)(0xFFFFFFFFu - (u32)i);
      u32 p = atomicAdd(&pcl, 1u);
      if (p < 256u) pbuf[p] = key;
    }
  }
  __syncthreads();
  if (t < 128 && sh[t]) atomicAdd(&hist[img * 2052 + 1921 + t], sh[t]);
  u32 n = min(pcl, 256u);
  if (t == 0) {
    if (qcl > 192u || pcl > 256u)
      atomicAdd(&pcnt[img], 1000000u);       // overflow -> fallback
    pbase = n ? atomicAdd(&pcnt[img], n) : 0u;
  }
  __syncthreads();
  for (u32 p = t; p < n; p += 256) {
    u32 dp = pbase + p;
    if (dp < 16384u) plist[(size_t)img * 16384 + dp] = pbuf[p];
  }
}

// K2 (FUSED thresh+compact): wave 0 suffix-scans bins [1921..2048] (2/lane),
// certifies T >= PREFILT, writes cab/Tarr/Marr. Then ALL 256 threads bin the
// ~10k prefiltered keys into sel segments using LDS counters (bins >= T are
// all in [1967,2048] -> 128-entry window). One less launch + LDS atomics.
__global__ void __launch_bounds__(256) k_thresh_compact(
    const u32* __restrict__ hist, const u64* __restrict__ plist,
    const u32* __restrict__ pcnt, int* __restrict__ Tarr,
    u32* __restrict__ cab, u32* __restrict__ Marr, u64* __restrict__ sel) {
  __shared__ u32 lcnt[128];                  // counters, bins [1921..2048]
  __shared__ int sT;
  int img = blockIdx.x;
  int t = threadIdx.x;
  if (t < 128) lcnt[t] = 0;
  if (t < 64) {
    int l = t;
    const u32* hb = hist + img * 2052;
    u32 v0 = hb[1921 + 2 * l];
    u32 v1 = hb[1922 + 2 * l];
    u32 csum = v0 + v1;
    u32 sfx = csum;                          // suffix-incl over lanes >= l
    for (int off = 1; off < 64; off <<= 1) {
      u32 tv = __shfl_down(sfx, off);
      if (l + off < 64) sfx += tv;
    }
    u32 excl = sfx - csum;                   // bins > 1922+2l
    u32* cb = cab + img * 2052;
    cb[1921 + 2 * l] = excl + v1;            // #keys in bins > 1921+2l
    cb[1922 + 2 * l] = excl;                 // #keys in bins > 1922+2l
    u32 sfxP = __shfl(excl, 22);             // = cab[1966] = #keys >= bin 1967
    bool ok = (sfxP >= (u32)PRE);
    if (l == 0 && !ok) { Tarr[img] = -1; Marr[img] = 0; sT = -1; }
    if (ok && excl < (u32)PRE && sfx >= (u32)PRE) {  // unique crossing lane
      int T; u32 M;
      if (excl + v1 >= (u32)PRE) { T = 1922 + 2 * l; M = excl + v1; }
      else                       { T = 1921 + 2 * l; M = sfx; }
      Tarr[img] = T; Marr[img] = M; sT = T;  // ok => T >= PREFILT
    }
  }
  __syncthreads();
  int T = sT;
  u32 P = pcnt[img];
  if (T < PREFILT || P > 16384u) return;     // fallback path handles
  const u32* cb = cab + img * 2052;
  for (u32 i = t; i < P; i += 256) {
    u64 key = plist[(size_t)img * 16384 + i];
    int bin = bin_of((u32)(key >> 32));
    if (bin >= T) {                          // bin in [1967,2048]
      u32 p = atomicAdd(&lcnt[bin - 1921], 1u);
      u32 dst = cb[bin] + p;
      if (dst < 16384u) sel[(size_t)img * 16384 + dst] = key;
    }
  }
}

// K2b FALLBACK histogram: full decode, adds ONLY bins < PREFILT. Gated.
__global__ void k_hist_fb(const float4* __restrict__ anch, const float2* __restrict__ probs,
                          const float4* __restrict__ delt, const int* __restrict__ Tarr,
                          u32* __restrict__ hist) {
  int img = blockIdx.y;
  if (Tarr[img] >= 0) return;
  __shared__ u32 sh[NBIN];
  int t = threadIdx.x;
  for (int p = t; p < NBIN; p += 256) sh[p] = 0;
  __syncthreads();
  int base = blockIdx.x * 1024;
  for (int r = 0; r < 4; r++) {
    int i = base + r * 256 + t;
    float4 a = anch[i];
    float4 d = delt[(size_t)img * N + i];
    float s = probs[(size_t)img * N + i].y;
    float x1, y1, x2, y2; bool valid;
    box_from(a, d, x1, y1, x2, y2, valid);
    int bin = valid ? (1 + min(2047, (int)(s * 2048.0f))) : 0;
    if (bin < PREFILT) atomicAdd(&sh[bin], 1u);
  }
  __syncthreads();
  for (int p = t; p < NBIN; p += 256)
    if (sh[p]) atomicAdd(&hist[img * 2052 + p], sh[p]);
}

// K2c FALLBACK thresh: the original full-range scan. Gated on Tarr<0.
__global__ void k_thresh_fb(const u32* __restrict__ hist, int* __restrict__ Tarr,
                            u32* __restrict__ cab, u32* __restrict__ Marr) {
  int img = blockIdx.x;
  if (Tarr[img] >= 0) return;
  int l = threadIdx.x;                       // 64 lanes
  const u32* hb = hist + img * 2052;
  u32 v[32];
  u32 csum = 0;
#pragma unroll
  for (int k = 0; k < 32; k++) { v[k] = hb[l * 32 + 1 + k]; csum += v[k]; }
  u32 sfx = csum;
  for (int off = 1; off < 64; off <<= 1) {
    u32 tv = __shfl_down(sfx, off);
    if (l + off < 64) sfx += tv;
  }
  u32 excl = sfx - csum;
  u32 ss = 0;
  u32 outv[32];
#pragma unroll
  for (int k = 31; k >= 0; k--) { outv[k] = ss + excl; ss += v[k]; }
  u32* cb = cab + img * 2052;
#pragma unroll
  for (int k = 0; k < 32; k++) cb[l * 32 + 1 + k] = outv[k];
  u32 total = __shfl(sfx, 0);
  if (l == 0) cb[0] = total;
  if (l == 0 && total < PRE) { Tarr[img] = 0; Marr[img] = 16384u; }
  if (excl < PRE && sfx >= PRE) {
    u32 acc = excl; int T = 0; u32 Mv = 0;
#pragma unroll
    for (int k = 31; k >= 0; k--) {
      acc += v[k];
      if (acc >= PRE) { T = l * 32 + 1 + k; Mv = acc; break; }
    }
    Tarr[img] = T; Marr[img] = Mv;
  }
}

// K3b: FALLBACK compact — full decode, only when prefilter insufficient.
__global__ void k_compact_fb(const float4* __restrict__ anch, const float2* __restrict__ probs,
                             const float4* __restrict__ delt, const u32* __restrict__ pcnt,
                             const int* __restrict__ Tarr, const u32* __restrict__ cab,
                             u32* __restrict__ bincnt, u64* __restrict__ sel) {
  int t = threadIdx.x, img = blockIdx.y;
  int T = Tarr[img];
  u32 P = pcnt[img];
  if (T >= PREFILT && P <= 16384u) return;   // fast path handled it
  const u32* cb = cab + img * 2052;
  for (int chunk = 0; chunk < 32; chunk++) { // 32 blocks x 32 chunks x 256
    int i = (blockIdx.x * 32 + chunk) * 256 + t;
    float4 a = anch[i];
    float4 d = delt[(size_t)img * N + i];
    float s = probs[(size_t)img * N + i].y;
    float x1, y1, x2, y2; bool valid;
    box_from(a, d, x1, y1, x2, y2, valid);
    int bin = valid ? (1 + min(2047, (int)(s * 2048.0f))) : 0;
    if (bin >= T) {
      u64 key = ((u64)(valid ? (__float_as_uint(s) | 0x80000000u) : 0u) << 32)
              | (u64)(0xFFFFFFFFu - (u32)i);
      u32 p = atomicAdd(&bincnt[img * 2052 + bin], 1u);
      u32 dst = cb[bin] + p;
      if (dst < 16384u) sel[(size_t)img * 16384 + dst] = key;
    }
  }
}

// K4: within-bin exact rank (~128 keys/segment). rank = cab[bin] + within;
// rank < PRE -> decode box (only 6000/img), scatter, set validw bit.
__global__ void k_rank(const u64* __restrict__ sel, const u32* __restrict__ cab,
                       const u32* __restrict__ hist, const u32* __restrict__ Marr,
                       const float4* __restrict__ anch, const float4* __restrict__ delt,
                       float4* __restrict__ boxes, u64* __restrict__ validw) {
  int t = threadIdx.x, img = blockIdx.y;
  u32 M = min(Marr[img], 16384u);
  u32 ci = blockIdx.x * 256u + (u32)t;
  if (ci >= M) return;
  const u64* sb = sel + (size_t)img * 16384;
  u64 key = sb[ci];
  u32 u = (u32)(key >> 32);
  int bin = bin_of(u);
  const u32* cb = cab + img * 2052;
  u32 segs = cb[bin];
  u32 sege;
  if (bin > 0) sege = cb[bin - 1];
  else         sege = min(16384u, segs + hist[img * 2052 + 0]);
  if (sege > 16384u) sege = 16384u;
  u32 within = 0;
  u32 j = segs;
  for (; j + 4 <= sege; j += 4) {
    within += (sb[j]     > key);
    within += (sb[j + 1] > key);
    within += (sb[j + 2] > key);
    within += (sb[j + 3] > key);
  }
  for (; j < sege; j++) within += (sb[j] > key);
  u32 rank = segs + within;
  if (rank < PRE) {
    u32 gi = 0xFFFFFFFFu - (u32)(key & 0xFFFFFFFFull);
    float4 a = anch[gi];
    float4 d = delt[(size_t)img * N + gi];
    float x1, y1, x2, y2; bool valid;
    box_from(a, d, x1, y1, x2, y2, valid);
    boxes[(size_t)img * 6016 + rank] = make_float4(x1, y1, x2, y2);
    if (u != 0u)
      atomicOr(&validw[img * 96 + (rank >> 6)], 1ull << (rank & 63));
  }
}

// K5a: fast-region IoU — one tile per block, 4 waves split by column
// quarters; fixed costs (decode, staging, flush) paid once per block.
__global__ void __launch_bounds__(256) k_mask(
    const float4* __restrict__ boxes, u64* __restrict__ dwbuf,
    u32* __restrict__ ecnt, u32* __restrict__ edges) {
  __shared__ float4 cbox[64];
  __shared__ float  carea[64];
  __shared__ u64 pb[4][64];
  __shared__ u32 ebuf[256];
  __shared__ u32 ecl, ebase;
  int t = threadIdx.x;
  int l = t & 63, w = t >> 6;
  int img = blockIdx.y;
  int tid = blockIdx.x;                      // tile id in [0, NTILE)
  float disc = (float)((2 * CW + 1) * (2 * CW + 1) - 8 * tid);
  int rb = (int)(((float)(2 * CW + 1) - sqrtf(disc)) * 0.5f);
  if (rb < 0) rb = 0;
  if (rb > CW - 1) rb = CW - 1;
  while (rb > 0 && (rb * CW - (rb * (rb - 1)) / 2) > tid) rb--;
  while (((rb + 1) * CW - ((rb + 1) * rb) / 2) <= tid) rb++;
  int cb = rb + (tid - (rb * CW - (rb * (rb - 1)) / 2));
  if (t == 0) ecl = 0;
  const float4* bb = boxes + (size_t)img * 6016;
  if (t < 64) {
    float4 c = bb[cb * 64 + t];
    cbox[t] = c;
    carea[t] = (c.z - c.x) * (c.w - c.y);
  }
  __syncthreads();                           // staging visible to all waves
  int r = rb * 64 + l;
  float4 rx = bb[r];
  float ra = (rx.z - rx.x) * (rx.w - rx.y);
  bool diag = (cb == rb);                    // block-uniform
  int c0 = w * 16;                           // this wave's column quarter
  if (diag) {
    u64 bits = 0ull;
    {
#pragma clang fp contract(off)
#pragma unroll
      for (int mm = 0; mm < 16; mm++) {
        int m = c0 + mm;
        float4 cx = cbox[m];
        float xx1 = fmaxf(rx.x, cx.x);
        float yy1 = fmaxf(rx.y, cx.y);
        float xx2 = fminf(rx.z, cx.z);
        float yy2 = fminf(rx.w, cx.w);
        float inter = fmaxf(xx2 - xx1, 0.0f) * fmaxf(yy2 - yy1, 0.0f);
        float denom = ra + carea[m] - inter + 1e-9f;
        if (iou_gt(inter, denom) && m != l) bits |= (1ull << m);
      }
    }
    pb[w][l] = bits;
    __syncthreads();
    if (t < 64)
      dwbuf[((size_t)img * CW + cb) * 64 + t] =
          pb[0][t] | pb[1][t] | pb[2][t] | pb[3][t];
  } else {
    {
#pragma clang fp contract(off)
#pragma unroll
      for (int mm = 0; mm < 16; mm++) {
        int m = c0 + mm;
        float4 cx = cbox[m];
        float xx1 = fmaxf(rx.x, cx.x);
        float yy1 = fmaxf(rx.y, cx.y);
        float xx2 = fminf(rx.z, cx.z);
        float yy2 = fminf(rx.w, cx.w);
        float inter = fmaxf(xx2 - xx1, 0.0f) * fmaxf(yy2 - yy1, 0.0f);
        float denom = ra + carea[m] - inter + 1e-9f;
        if (__builtin_expect(iou_gt(inter, denom), 0)) {
          u32 p = atomicAdd(&ecl, 1u);
          if (p < 256u) ebuf[p] = (((u32)(cb * 64 + m)) << 16) | (u32)r;
        }
      }
    }
    __syncthreads();                         // edges all emitted
    u32 n = min(ecl, 256u);
    if (n != 0u) {                           // uniform condition
      if (t == 0) {
        if (ecl > 256u) atomicAdd(&ecnt[img], 1000000u); // overflow->rescue
        ebase = atomicAdd(&ecnt[img], n);
      }
      __syncthreads();
      for (u32 p = t; p < n; p += 256) {
        u32 dp = ebase + p;
        if (dp < ECAP) edges[(size_t)img * ECAP + dp] = ebuf[p];
      }
    }
  }
}

// K5b: rescue — computes the ENTIRE upper triangle into mask. No-op if okf=1.
__global__ void k_mask_rest(const float4* __restrict__ boxes, u64* __restrict__ mask,
                            const u32* __restrict__ okf) {
  int rb = blockIdx.x, img = blockIdx.y;
  if (okf[img]) return;
  __shared__ float4 cbox[4][64];
  __shared__ float  carea[4][64];
  int t = threadIdx.x;
  int rl = t & 63, g = t >> 6;
  const float4* bb = boxes + (size_t)img * 6016;
  int r = rb * 64 + rl;
  float4 rx = bb[r];
  float ra = (rx.z - rx.x) * (rx.w - rx.y);
  u64* mimg = mask + (size_t)img * 94 * 6000;
  int cb0 = rb;                              // full triangle on rescue
  int jmax = (94 - cb0 + 3) >> 2;
  for (int j = 0; j < jmax; j++) {
    int cb = cb0 + g + 4 * j;
    bool act = cb < 94;
    __syncthreads();
    if (act) {
      float4 c = bb[cb * 64 + rl];
      cbox[g][rl] = c;
      carea[g][rl] = (c.z - c.x) * (c.w - c.y);
    }
    __syncthreads();
    if (act) {
#pragma clang fp contract(off)
      u64 bits = 0ull;
      for (int m = 0; m < 64; m++) {
        float4 cx = cbox[g][m];
        float xx1 = fmaxf(rx.x, cx.x);
        float yy1 = fmaxf(rx.y, cx.y);
        float xx2 = fminf(rx.z, cx.z);
        float yy2 = fminf(rx.w, cx.w);
        float inter = fmaxf(xx2 - xx1, 0.0f) * fmaxf(yy2 - yy1, 0.0f);
        float denom = ra + carea[g][m] - inter + 1e-9f;
        int c_j = cb * 64 + m;
        if (iou_gt(inter, denom) && c_j != r) bits |= (1ull << m);
      }
      if (r < PRE) mimg[(size_t)cb * 6000 + r] = bits;
    }
  }
}

// K6a: LEVEL-SYNCHRONOUS greedy NMS (R14, verified). Diag words from dwbuf.
__global__ void __launch_bounds__(64, 1) k_scan_fast(
    const u64* __restrict__ dwbuf, const u64* __restrict__ validw,
    const float4* __restrict__ boxes, float4* __restrict__ out,
    u32* __restrict__ okf, const u32* __restrict__ ecnt,
    const u32* __restrict__ edges) {
  __shared__ u64 dw[CW * 64];                // diag blocks
  __shared__ u64 al[CW], fw[CW], kp[CW], blkX[CW], supX[CW];
  __shared__ u32 eb[ECAP];                   // edge list
  __shared__ unsigned short list[KOUT];
  int l = threadIdx.x;
  int img = blockIdx.x;
  for (int c = 0; c < CW; c++)
    dw[c * 64 + l] = dwbuf[((size_t)img * CW + c) * 64 + l];
  u32 E = ecnt[img];
  if (E > (u32)ECAP) { if (l == 0) okf[img] = 0u; return; }
  for (u32 p = l; p < E; p += 64) eb[p] = edges[(size_t)img * ECAP + p];
  if (l < CW) {
    al[l] = validw[img * 96 + l];
    kp[l] = 0ull; blkX[l] = 0ull; supX[l] = 0ull;
  }
  __syncthreads();
  u64 lmask = (1ull << l) - 1ull;            // earlier-in-chunk rows
  bool fail = false;
  for (int round = 0; ; round++) {
    u64 anyv = (l < CW) ? al[l] : 0ull;
#pragma unroll
    for (int off = 32; off >= 1; off >>= 1) anyv |= __shfl_xor(anyv, off);
    if (anyv == 0ull) break;                 // all rows decided
    if (round >= RMAX) { fail = true; break; }
    for (u32 p = l; p < E; p += 64) {
      u32 e = eb[p];
      u32 tgt = e >> 16, src = e & 0xFFFFu;
      if ((al[src >> 6] >> (src & 63u)) & 1ull)
        atomicOr(&blkX[tgt >> 6], 1ull << (tgt & 63u));
    }
    for (int c = 0; c < CW; c++) {
      u64 a_c = al[c];
      u64 dj = dw[c * 64 + l];
      u64 blkin = __ballot((dj & a_c & lmask) != 0ull);
      if (l == 0) fw[c] = a_c & ~blkin & ~blkX[c];
    }
    for (u32 p = l; p < E; p += 64) {
      u32 e = eb[p];
      u32 tgt = e >> 16, src = e & 0xFFFFu;
      if ((fw[src >> 6] >> (src & 63u)) & 1ull)
        atomicOr(&supX[tgt >> 6], 1ull << (tgt & 63u));
    }
    for (int c = 0; c < CW; c++) {
      u64 f_c = fw[c];
      u64 dj = dw[c * 64 + l];
      u64 supin = __ballot((dj & f_c & lmask) != 0ull);
      if (l == 0) {
        kp[c] |= f_c;
        al[c] = al[c] & ~f_c & ~supin & ~supX[c];
      }
    }
    if (l < CW) { blkX[l] = 0ull; supX[l] = 0ull; }
  }
  u64 kw_l = (!fail && l < CW) ? kp[l] : 0ull;
  u32 pc = (u32)__popcll(kw_l);
  u32 pre = pc;
  for (int off = 1; off < 64; off <<= 1) {
    u32 v2 = __shfl_up(pre, off);
    if (l >= off) pre += v2;
  }
  u32 tot = __shfl(pre, 63);
  bool ok = !fail && (tot >= (u32)KOUT);
  if (l == 0) okf[img] = ok ? 1u : 0u;
  if (!ok) return;                           // rescue path takes over
  if (l < CW) {
    u32 b = pre - pc;
    u64 word = kw_l;
    while (word && b < (u32)KOUT) {
      int j = (int)__ffsll(word) - 1;
      word &= word - 1;
      list[b++] = (unsigned short)(l * 64 + j);
    }
  }
  __syncthreads();
  for (int p = l; p < KOUT; p += 64)
    out[(size_t)img * KOUT + p] = boxes[(size_t)img * 6016 + list[p]];
}

// K6b: full-depth rescue scan. No-op when fast scan succeeded.
__global__ void k_scan_full(const u64* __restrict__ mask, const u64* __restrict__ validw,
                            const float4* __restrict__ boxes, float4* __restrict__ out,
                            const u32* __restrict__ okf) {
  int img = blockIdx.x;
  if (okf[img]) return;
  __shared__ unsigned short kept[KOUT];
  int l = threadIdx.x;
  const u64* vw = validw + img * 96;
  u64 r0 = ~vw[l];
  u64 r1 = (l < MW - 64) ? ~vw[64 + l] : ~0ull;
  const u64* c0p = mask + ((size_t)img * 94 + l) * 6000;
  const u64* c1p = mask + ((size_t)img * 94 + (l < MW - 64 ? 64 + l : 0)) * 6000;

  u64 ca[16], cb[16], na[16], nb2[16];
#pragma unroll
  for (int k = 0; k < 16; k++) {
    ca[k] = c0p[k];
    cb[k] = (l < MW - 64) ? c1p[k] : 0ull;
  }
  int cnt = 0; bool done = false;
  for (int base = 0; base < PRE; base += 16) {
#pragma unroll
    for (int k = 0; k < 16; k++) {
      int rr = base + 16 + k;
      if (rr < PRE) {
        na[k]  = c0p[rr];
        nb2[k] = (l < MW - 64) ? c1p[rr] : 0ull;
      } else { na[k] = 0ull; nb2[k] = 0ull; }
    }
#pragma unroll
    for (int k = 0; k < 16; k++) {
      if (!done) {
        int i = base + k;
        int w = i >> 6;
        u64 wv = (w < 64) ? __shfl(r0, w) : __shfl(r1, w - 64);
        if (!((wv >> (i & 63)) & 1ull)) {
          if (l == 0 && cnt < KOUT) kept[cnt] = (unsigned short)i;
          cnt++;
          r0 |= (l >= w)        ? ca[k] : 0ull;
          r1 |= ((64 + l) >= w) ? cb[k] : 0ull;
          if (cnt >= KOUT) done = true;
        }
      }
    }
    if (done) break;
#pragma unroll
    for (int k = 0; k < 16; k++) { ca[k] = na[k]; cb[k] = nb2[k]; }
  }
  __syncthreads();
  for (int p = l; p < KOUT; p += 64) {
    float4 v = make_float4(0.f, 0.f, 0.f, 0.f);
    if (p < cnt) v = boxes[(size_t)img * 6016 + kept[p]];
    out[(size_t)img * KOUT + p] = v;
  }
}

extern "C" void kernel_launch(void* const* d_in, const int* in_sizes, int n_in,
                              void* d_out, int out_size, void* d_ws, size_t ws_size,
                              hipStream_t stream) {
  const float4* anch  = (const float4*)d_in[0];
  const float2* probs = (const float2*)d_in[1];
  const float4* delt  = (const float4*)d_in[2];
  float4* out = (float4*)d_out;
  char* ws = (char*)d_ws;
  (void)in_sizes; (void)n_in;

  if (ws_size < WS_NEED) {  // not enough scratch: write zeros, bail cleanly
    (void)hipMemsetAsync(d_out, 0, (size_t)out_size * sizeof(float), stream);
    return;
  }

  u64* mask    = (u64*)(ws + OFF_MASK);
  u64* sel     = (u64*)(ws + OFF_SEL);
  float4* bxs  = (float4*)(ws + OFF_BOX);
  u64* validw  = (u64*)(ws + OFF_VAL);
  u32* hist    = (u32*)(ws + OFF_HIST);
  u32* cab     = (u32*)(ws + OFF_CAB);
  u32* bincnt  = (u32*)(ws + OFF_BCNT);
  int* Tarr    = (int*)(ws + OFF_T);
  u32* Marr    = (u32*)(ws + OFF_M);
  u32* okf     = (u32*)(ws + OFF_FLAG);
  u32* ecnt    = (u32*)(ws + OFF_ECNT);
  u32* edges   = (u32*)(ws + OFF_EDG);
  u64* dwbuf   = (u64*)(ws + OFF_DW);
  u64* plist   = (u64*)(ws + OFF_PL);
  u32* pcnt    = (u32*)(ws + OFF_PCNT);

  k_zero<<<100, 256, 0, stream>>>((uint4*)(ws + OFF_VAL), (uint4*)(ws + OFF_PCNT));

  dim3 g1h(128, B);
  k_hist<<<g1h, 256, 0, stream>>>(anch, probs, delt, hist, bxs, plist, pcnt);
  k_thresh_compact<<<B, 256, 0, stream>>>(hist, plist, pcnt, Tarr, cab, Marr, sel);
  dim3 g1(256, B);
  k_hist_fb<<<g1, 256, 0, stream>>>(anch, probs, delt, Tarr, hist);
  k_thresh_fb<<<B, 64, 0, stream>>>(hist, Tarr, cab, Marr);
  dim3 g3b(32, B);
  k_compact_fb<<<g3b, 256, 0, stream>>>(anch, probs, delt, pcnt, Tarr, cab, bincnt, sel);
  dim3 g4(64, B);
  k_rank<<<g4, 256, 0, stream>>>(sel, cab, hist, Marr, anch, delt, bxs, validw);
  dim3 g5(NTILE, B);
  k_mask<<<g5, 256, 0, stream>>>(bxs, dwbuf, ecnt, edges);
  k_scan_fast<<<B, 64, 0, stream>>>(dwbuf, validw, bxs, out, okf, ecnt, edges);
  dim3 g5b(94, B);
  k_mask_rest<<<g5b, 256, 0, stream>>>(bxs, mask, okf);
  k_scan_full<<<B, 64, 0, stream>>>(mask, validw, bxs, out, okf);
}

// Round 31
// 155.548 us; speedup vs baseline: 1.0292x; 1.0292x over previous
//
#include <hip/hip_runtime.h>
#include <cstdint>

#define B 16
#define N 262144
#define PRE 6000
#define KOUT 1000
#define MW 94            // 64-bit mask words per row (6016 bits >= 6000)
#define CW 24            // fast-path chunks: rows 0..1535 (proven margin:
                         // expected keeps ~1190 >> 1000; CW=20 failed R29)
#define NTILE 300        // CW*(CW+1)/2 upper-triangle tiles
#define ECAP 4096        // per-image edge-list capacity
#define RMAX 64          // level-round cap before rescue
#define NBIN 2049
#define PREFILT 1967     // prefilter bin: E[keys above] ~9.9k >> 6k (40 sigma)
#define PGATE 0.9599609375f  // = 1966/2048 exactly; s >= PGATE <=> bin >= 1967
#define IMGMAX 511.0f
#define NMS_TH 0.7f

typedef unsigned int u32;
typedef unsigned long long u64;

// ---- workspace layout (bytes) ----
#define OFF_MASK  0ull                    // 16*94*6000*8         = 72,192,000 (rescue only)
#define OFF_SEL   72192000ull             // 16*16384*8           =  2,097,152
#define OFF_BOX   74289152ull             // 16*6016*16           =  1,540,096
#define OFF_VAL   75829248ull             // 16*96*8              =     12,288
#define OFF_HIST  75841536ull             // 16*2052*4            =    131,328
#define OFF_CAB   75972864ull             // 16*2052*4            =    131,328
#define OFF_BCNT  76104192ull             // 16*2052*4            =    131,328
#define OFF_T     76235520ull             // 16*4                 =         64
#define OFF_M     76235584ull             // 16*4                 =         64
#define OFF_FLAG  76235648ull             // 16*4                 =         64
#define OFF_ECNT  76235712ull             // 16*4                 =         64
#define OFF_EDG   76235776ull             // 16*4096*4            =    262,144
#define OFF_DW    76497920ull             // 16*CW*64*8           <=   327,680
#define OFF_PL    76825600ull             // 16*16384*8           =  2,097,152
#define OFF_PCNT  78922752ull             // 16*4                 =         64
#define WS_NEED   78922816ull
// zero region each call: OFF_VAL..OFF_EDG = 406,528 B (25,408 uint4) + pcnt

// Box decode — mirrors reference op order; contraction off so we don't fuse
// mul+add where XLA doesn't (keep/valid comparisons must match bit-for-bit).
__device__ __forceinline__ void box_from(const float4 a, const float4 d,
    float& x1, float& y1, float& x2, float& y2, bool& valid) {
#pragma clang fp contract(off)
  float w  = a.z - a.x;
  float h  = a.w - a.y;
  float cx = a.x + 0.5f * w;
  float cy = a.y + 0.5f * h;
  cx = cx + d.x * w;
  cy = cy + d.y * h;
  w = w * expf(d.z);
  h = h * expf(d.w);
  x1 = cx - 0.5f * w;
  y1 = cy - 0.5f * h;
  x2 = cx + 0.5f * w;
  y2 = cy + 0.5f * h;
  x1 = fminf(fmaxf(x1, 0.0f), IMGMAX);
  y1 = fminf(fmaxf(y1, 0.0f), IMGMAX);
  x2 = fminf(fmaxf(x2, 0.0f), IMGMAX);
  y2 = fminf(fmaxf(y2, 0.0f), IMGMAX);
  valid = ((x2 - x1) >= 16.0f) && ((y2 - y1) >= 16.0f);
}

// IoU > 0.7, bit-exact vs IEEE div, mul-form: d = inter - 0.7*denom
// (fp err <= ~3e-7*denom). |d| > 1e-4*denom -> sign decides (band 300x
// the error, provably agrees with div compare); borderline -> exact div.
__device__ __forceinline__ bool iou_gt(float inter, float denom) {
  float d = inter - NMS_TH * denom;
  if (__builtin_expect(fabsf(d) <= 1e-4f * denom, 0))
    return (inter / denom) > NMS_TH;
  return d > 0.0f;
}

__device__ __forceinline__ int bin_of(u32 u) {
  if (u == 0u) return 0;
  float s = __uint_as_float(u & 0x7FFFFFFFu);
  return 1 + min(2047, (int)(s * 2048.0f));
}

// K0: workspace zeroing (HIP's fill kernel ran this region at ~10 GB/s).
__global__ void __launch_bounds__(256) k_zero(uint4* __restrict__ a,
                                              uint4* __restrict__ b) {
  int i = blockIdx.x * 256 + threadIdx.x;
  if (i < 25408) a[i] = make_uint4(0u, 0u, 0u, 0u);
  if (i < 4)     b[i] = make_uint4(0u, 0u, 0u, 0u);
}

// K1 (LIGHT, TWO-PHASE): phase A scans 8 scores/thread (float4 stream) and
// queues gated indices to LDS; phase B decodes the queue in parallel.
__global__ void k_hist(const float4* __restrict__ anch, const float2* __restrict__ probs,
                       const float4* __restrict__ delt, u32* __restrict__ hist,
                       float4* __restrict__ boxes, u64* __restrict__ plist,
                       u32* __restrict__ pcnt) {
  __shared__ u32 sh[128];                    // bins [1921..2048]
  __shared__ u64 qbuf[192];                  // gated (score,idx)
  __shared__ u64 pbuf[256];                  // valid keys
  __shared__ u32 qcl, pcl, pbase;
  int t = threadIdx.x;
  int img = blockIdx.y;
  if (t == 0) { qcl = 0; pcl = 0; }
  if (blockIdx.x == 0 && t < 16)
    boxes[(size_t)img * 6016 + 6000 + t] = make_float4(0.f, 0.f, 0.f, 0.f);
  if (t < 128) sh[t] = 0;
  __syncthreads();
  const float4* pr4 = (const float4*)(probs + (size_t)img * N);  // 16B-aligned
  int b4 = blockIdx.x * 1024 + t;            // 1024 f4 = 2048 anchors/block
  float4 p0 = pr4[b4];
  float4 p1 = pr4[b4 + 256];
  float4 p2 = pr4[b4 + 512];
  float4 p3 = pr4[b4 + 768];
  auto check = [&](float s, int i) {
    if (s >= PGATE) {                        // exact gate for bin >= PREFILT
      u32 q = atomicAdd(&qcl, 1u);
      if (q < 192u)
        qbuf[q] = ((u64)__float_as_uint(s) << 32) | (u64)(u32)i;
    }
  };
  check(p0.y, 2 * b4);            check(p0.w, 2 * b4 + 1);
  check(p1.y, 2 * (b4 + 256));    check(p1.w, 2 * (b4 + 256) + 1);
  check(p2.y, 2 * (b4 + 512));    check(p2.w, 2 * (b4 + 512) + 1);
  check(p3.y, 2 * (b4 + 768));    check(p3.w, 2 * (b4 + 768) + 1);
  __syncthreads();
  u32 qn = min(qcl, 192u);
  for (u32 q = t; q < qn; q += 256) {        // parallel decode of the queue
    u64 qv = qbuf[q];
    float s = __uint_as_float((u32)(qv >> 32));
    int i = (int)(u32)qv;
    float4 a = anch[i];
    float4 d = delt[(size_t)img * N + i];
    float x1, y1, x2, y2; bool valid;
    box_from(a, d, x1, y1, x2, y2, valid);
    if (valid) {
      int bin = 1 + min(2047, (int)(s * 2048.0f));   // >= PREFILT
      atomicAdd(&sh[bin - 1921], 1u);
      u64 key = ((u64)(__float_as_uint(s) | 0x80000000u) << 32)
              | (u64)(0xFFFFFFFFu - (u32)i);
      u32 p = atomicAdd(&pcl, 1u);
      if (p < 256u) pbuf[p] = key;
    }
  }
  __syncthreads();
  if (t < 128 && sh[t]) atomicAdd(&hist[img * 2052 + 1921 + t], sh[t]);
  u32 n = min(pcl, 256u);
  if (t == 0) {
    if (qcl > 192u || pcl > 256u)
      atomicAdd(&pcnt[img], 1000000u);       // overflow -> fallback
    pbase = n ? atomicAdd(&pcnt[img], n) : 0u;
  }
  __syncthreads();
  for (u32 p = t; p < n; p += 256) {
    u32 dp = pbase + p;
    if (dp < 16384u) plist[(size_t)img * 16384 + dp] = pbuf[p];
  }
}

// K2 (LIGHT): suffix-scan over bins [1921..2048] (2 bins/lane). Certifies
// ok <=> sfx(PREFILT) >= PRE <=> T >= PREFILT; then T,M + cab[1921..2048].
__global__ void k_thresh(const u32* __restrict__ hist, int* __restrict__ Tarr,
                         u32* __restrict__ cab, u32* __restrict__ Marr) {
  int img = blockIdx.x;
  int l = threadIdx.x;                       // 64 lanes
  const u32* hb = hist + img * 2052;
  u32 v0 = hb[1921 + 2 * l];
  u32 v1 = hb[1922 + 2 * l];
  u32 csum = v0 + v1;
  u32 sfx = csum;                            // suffix-incl over lanes >= l
  for (int off = 1; off < 64; off <<= 1) {
    u32 tv = __shfl_down(sfx, off);
    if (l + off < 64) sfx += tv;
  }
  u32 excl = sfx - csum;                     // bins > 1922+2l
  u32* cb = cab + img * 2052;
  cb[1921 + 2 * l] = excl + v1;              // #keys in bins > 1921+2l
  cb[1922 + 2 * l] = excl;                   // #keys in bins > 1922+2l
  u32 sfxP = __shfl(excl, 22);               // = cab[1966] = #bins >= 1967
  bool ok = (sfxP >= (u32)PRE);
  if (l == 0 && !ok) { Tarr[img] = -1; Marr[img] = 0; }
  if (ok && excl < (u32)PRE && sfx >= (u32)PRE) {  // unique crossing lane
    int T; u32 M;
    if (excl + v1 >= (u32)PRE) { T = 1922 + 2 * l; M = excl + v1; }
    else                       { T = 1921 + 2 * l; M = sfx; }
    Tarr[img] = T; Marr[img] = M;            // ok => T >= PREFILT
  }
}

// K2b FALLBACK histogram: full decode, adds ONLY bins < PREFILT. Gated.
__global__ void k_hist_fb(const float4* __restrict__ anch, const float2* __restrict__ probs,
                          const float4* __restrict__ delt, const int* __restrict__ Tarr,
                          u32* __restrict__ hist) {
  int img = blockIdx.y;
  if (Tarr[img] >= 0) return;
  __shared__ u32 sh[NBIN];
  int t = threadIdx.x;
  for (int p = t; p < NBIN; p += 256) sh[p] = 0;
  __syncthreads();
  int base = blockIdx.x * 1024;
  for (int r = 0; r < 4; r++) {
    int i = base + r * 256 + t;
    float4 a = anch[i];
    float4 d = delt[(size_t)img * N + i];
    float s = probs[(size_t)img * N + i].y;
    float x1, y1, x2, y2; bool valid;
    box_from(a, d, x1, y1, x2, y2, valid);
    int bin = valid ? (1 + min(2047, (int)(s * 2048.0f))) : 0;
    if (bin < PREFILT) atomicAdd(&sh[bin], 1u);
  }
  __syncthreads();
  for (int p = t; p < NBIN; p += 256)
    if (sh[p]) atomicAdd(&hist[img * 2052 + p], sh[p]);
}

// K2c FALLBACK thresh: the original full-range scan. Gated on Tarr<0.
__global__ void k_thresh_fb(const u32* __restrict__ hist, int* __restrict__ Tarr,
                            u32* __restrict__ cab, u32* __restrict__ Marr) {
  int img = blockIdx.x;
  if (Tarr[img] >= 0) return;
  int l = threadIdx.x;                       // 64 lanes
  const u32* hb = hist + img * 2052;
  u32 v[32];
  u32 csum = 0;
#pragma unroll
  for (int k = 0; k < 32; k++) { v[k] = hb[l * 32 + 1 + k]; csum += v[k]; }
  u32 sfx = csum;
  for (int off = 1; off < 64; off <<= 1) {
    u32 tv = __shfl_down(sfx, off);
    if (l + off < 64) sfx += tv;
  }
  u32 excl = sfx - csum;
  u32 ss = 0;
  u32 outv[32];
#pragma unroll
  for (int k = 31; k >= 0; k--) { outv[k] = ss + excl; ss += v[k]; }
  u32* cb = cab + img * 2052;
#pragma unroll
  for (int k = 0; k < 32; k++) cb[l * 32 + 1 + k] = outv[k];
  u32 total = __shfl(sfx, 0);
  if (l == 0) cb[0] = total;
  if (l == 0 && total < PRE) { Tarr[img] = 0; Marr[img] = 16384u; }
  if (excl < PRE && sfx >= PRE) {
    u32 acc = excl; int T = 0; u32 Mv = 0;
#pragma unroll
    for (int k = 31; k >= 0; k--) {
      acc += v[k];
      if (acc >= PRE) { T = l * 32 + 1 + k; Mv = acc; break; }
    }
    Tarr[img] = T; Marr[img] = Mv;
  }
}

// K3a: FAST compact — bins the ~10k prefiltered keys into sel segments.
__global__ void k_compact_fast(const u64* __restrict__ plist, const u32* __restrict__ pcnt,
                               const int* __restrict__ Tarr, const u32* __restrict__ cab,
                               u32* __restrict__ bincnt, u64* __restrict__ sel) {
  int t = threadIdx.x, img = blockIdx.y;
  int T = Tarr[img];
  u32 P = pcnt[img];
  if (T < PREFILT || P > 16384u) return;     // fallback path handles
  const u32* cb = cab + img * 2052;
  for (u32 i = blockIdx.x * 256u + (u32)t; i < P; i += 8u * 256u) {
    u64 key = plist[(size_t)img * 16384 + i];
    int bin = bin_of((u32)(key >> 32));
    if (bin >= T) {
      u32 p = atomicAdd(&bincnt[img * 2052 + bin], 1u);
      u32 dst = cb[bin] + p;
      if (dst < 16384u) sel[(size_t)img * 16384 + dst] = key;
    }
  }
}

// K3b: FALLBACK compact — full decode, only when prefilter insufficient.
__global__ void k_compact_fb(const float4* __restrict__ anch, const float2* __restrict__ probs,
                             const float4* __restrict__ delt, const u32* __restrict__ pcnt,
                             const int* __restrict__ Tarr, const u32* __restrict__ cab,
                             u32* __restrict__ bincnt, u64* __restrict__ sel) {
  int t = threadIdx.x, img = blockIdx.y;
  int T = Tarr[img];
  u32 P = pcnt[img];
  if (T >= PREFILT && P <= 16384u) return;   // fast path handled it
  const u32* cb = cab + img * 2052;
  for (int chunk = 0; chunk < 32; chunk++) { // 32 blocks x 32 chunks x 256
    int i = (blockIdx.x * 32 + chunk) * 256 + t;
    float4 a = anch[i];
    float4 d = delt[(size_t)img * N + i];
    float s = probs[(size_t)img * N + i].y;
    float x1, y1, x2, y2; bool valid;
    box_from(a, d, x1, y1, x2, y2, valid);
    int bin = valid ? (1 + min(2047, (int)(s * 2048.0f))) : 0;
    if (bin >= T) {
      u64 key = ((u64)(valid ? (__float_as_uint(s) | 0x80000000u) : 0u) << 32)
              | (u64)(0xFFFFFFFFu - (u32)i);
      u32 p = atomicAdd(&bincnt[img * 2052 + bin], 1u);
      u32 dst = cb[bin] + p;
      if (dst < 16384u) sel[(size_t)img * 16384 + dst] = key;
    }
  }
}

// K4: within-bin exact rank (~128 keys/segment). rank = cab[bin] + within;
// rank < PRE -> decode box (only 6000/img), scatter, set validw bit.
__global__ void k_rank(const u64* __restrict__ sel, const u32* __restrict__ cab,
                       const u32* __restrict__ hist, const u32* __restrict__ Marr,
                       const float4* __restrict__ anch, const float4* __restrict__ delt,
                       float4* __restrict__ boxes, u64* __restrict__ validw) {
  int t = threadIdx.x, img = blockIdx.y;
  u32 M = min(Marr[img], 16384u);
  u32 ci = blockIdx.x * 256u + (u32)t;
  if (ci >= M) return;
  const u64* sb = sel + (size_t)img * 16384;
  u64 key = sb[ci];
  u32 u = (u32)(key >> 32);
  int bin = bin_of(u);
  const u32* cb = cab + img * 2052;
  u32 segs = cb[bin];
  u32 sege;
  if (bin > 0) sege = cb[bin - 1];
  else         sege = min(16384u, segs + hist[img * 2052 + 0]);
  if (sege > 16384u) sege = 16384u;
  u32 within = 0;
  u32 j = segs;
  for (; j + 4 <= sege; j += 4) {
    within += (sb[j]     > key);
    within += (sb[j + 1] > key);
    within += (sb[j + 2] > key);
    within += (sb[j + 3] > key);
  }
  for (; j < sege; j++) within += (sb[j] > key);
  u32 rank = segs + within;
  if (rank < PRE) {
    u32 gi = 0xFFFFFFFFu - (u32)(key & 0xFFFFFFFFull);
    float4 a = anch[gi];
    float4 d = delt[(size_t)img * N + gi];
    float x1, y1, x2, y2; bool valid;
    box_from(a, d, x1, y1, x2, y2, valid);
    boxes[(size_t)img * 6016 + rank] = make_float4(x1, y1, x2, y2);
    if (u != 0u)
      atomicOr(&validw[img * 96 + (rank >> 6)], 1ull << (rank & 63));
  }
}

// K5a: fast-region IoU — one tile per block, 4 waves split by column
// quarters; fixed costs (decode, staging, flush) paid once per block.
__global__ void __launch_bounds__(256) k_mask(
    const float4* __restrict__ boxes, u64* __restrict__ dwbuf,
    u32* __restrict__ ecnt, u32* __restrict__ edges) {
  __shared__ float4 cbox[64];
  __shared__ float  carea[64];
  __shared__ u64 pb[4][64];
  __shared__ u32 ebuf[256];
  __shared__ u32 ecl, ebase;
  int t = threadIdx.x;
  int l = t & 63, w = t >> 6;
  int img = blockIdx.y;
  int tid = blockIdx.x;                      // tile id in [0, NTILE)
  float disc = (float)((2 * CW + 1) * (2 * CW + 1) - 8 * tid);
  int rb = (int)(((float)(2 * CW + 1) - sqrtf(disc)) * 0.5f);
  if (rb < 0) rb = 0;
  if (rb > CW - 1) rb = CW - 1;
  while (rb > 0 && (rb * CW - (rb * (rb - 1)) / 2) > tid) rb--;
  while (((rb + 1) * CW - ((rb + 1) * rb) / 2) <= tid) rb++;
  int cb = rb + (tid - (rb * CW - (rb * (rb - 1)) / 2));
  if (t == 0) ecl = 0;
  const float4* bb = boxes + (size_t)img * 6016;
  if (t < 64) {
    float4 c = bb[cb * 64 + t];
    cbox[t] = c;
    carea[t] = (c.z - c.x) * (c.w - c.y);
  }
  __syncthreads();                           // staging visible to all waves
  int r = rb * 64 + l;
  float4 rx = bb[r];
  float ra = (rx.z - rx.x) * (rx.w - rx.y);
  bool diag = (cb == rb);                    // block-uniform
  int c0 = w * 16;                           // this wave's column quarter
  if (diag) {
    u64 bits = 0ull;
    {
#pragma clang fp contract(off)
#pragma unroll
      for (int mm = 0; mm < 16; mm++) {
        int m = c0 + mm;
        float4 cx = cbox[m];
        float xx1 = fmaxf(rx.x, cx.x);
        float yy1 = fmaxf(rx.y, cx.y);
        float xx2 = fminf(rx.z, cx.z);
        float yy2 = fminf(rx.w, cx.w);
        float inter = fmaxf(xx2 - xx1, 0.0f) * fmaxf(yy2 - yy1, 0.0f);
        float denom = ra + carea[m] - inter + 1e-9f;
        if (iou_gt(inter, denom) && m != l) bits |= (1ull << m);
      }
    }
    pb[w][l] = bits;
    __syncthreads();
    if (t < 64)
      dwbuf[((size_t)img * CW + cb) * 64 + t] =
          pb[0][t] | pb[1][t] | pb[2][t] | pb[3][t];
  } else {
    {
#pragma clang fp contract(off)
#pragma unroll
      for (int mm = 0; mm < 16; mm++) {
        int m = c0 + mm;
        float4 cx = cbox[m];
        float xx1 = fmaxf(rx.x, cx.x);
        float yy1 = fmaxf(rx.y, cx.y);
        float xx2 = fminf(rx.z, cx.z);
        float yy2 = fminf(rx.w, cx.w);
        float inter = fmaxf(xx2 - xx1, 0.0f) * fmaxf(yy2 - yy1, 0.0f);
        float denom = ra + carea[m] - inter + 1e-9f;
        if (__builtin_expect(iou_gt(inter, denom), 0)) {
          u32 p = atomicAdd(&ecl, 1u);
          if (p < 256u) ebuf[p] = (((u32)(cb * 64 + m)) << 16) | (u32)r;
        }
      }
    }
    __syncthreads();                         // edges all emitted
    u32 n = min(ecl, 256u);
    if (n != 0u) {                           // uniform condition
      if (t == 0) {
        if (ecl > 256u) atomicAdd(&ecnt[img], 1000000u); // overflow->rescue
        ebase = atomicAdd(&ecnt[img], n);
      }
      __syncthreads();
      for (u32 p = t; p < n; p += 256) {
        u32 dp = ebase + p;
        if (dp < ECAP) edges[(size_t)img * ECAP + dp] = ebuf[p];
      }
    }
  }
}

// K5b: rescue — computes the ENTIRE upper triangle into mask. No-op if okf=1.
__global__ void k_mask_rest(const float4* __restrict__ boxes, u64* __restrict__ mask,
                            const u32* __restrict__ okf) {
  int rb = blockIdx.x, img = blockIdx.y;
  if (okf[img]) return;
  __shared__ float4 cbox[4][64];
  __shared__ float  carea[4][64];
  int t = threadIdx.x;
  int rl = t & 63, g = t >> 6;
  const float4* bb = boxes + (size_t)img * 6016;
  int r = rb * 64 + rl;
  float4 rx = bb[r];
  float ra = (rx.z - rx.x) * (rx.w - rx.y);
  u64* mimg = mask + (size_t)img * 94 * 6000;
  int cb0 = rb;                              // full triangle on rescue
  int jmax = (94 - cb0 + 3) >> 2;
  for (int j = 0; j < jmax; j++) {
    int cb = cb0 + g + 4 * j;
    bool act = cb < 94;
    __syncthreads();
    if (act) {
      float4 c = bb[cb * 64 + rl];
      cbox[g][rl] = c;
      carea[g][rl] = (c.z - c.x) * (c.w - c.y);
    }
    __syncthreads();
    if (act) {
#pragma clang fp contract(off)
      u64 bits = 0ull;
      for (int m = 0; m < 64; m++) {
        float4 cx = cbox[g][m];
        float xx1 = fmaxf(rx.x, cx.x);
        float yy1 = fmaxf(rx.y, cx.y);
        float xx2 = fminf(rx.z, cx.z);
        float yy2 = fminf(rx.w, cx.w);
        float inter = fmaxf(xx2 - xx1, 0.0f) * fmaxf(yy2 - yy1, 0.0f);
        float denom = ra + carea[g][m] - inter + 1e-9f;
        int c_j = cb * 64 + m;
        if (iou_gt(inter, denom) && c_j != r) bits |= (1ull << m);
      }
      if (r < PRE) mimg[(size_t)cb * 6000 + r] = bits;
    }
  }
}

// K6a: LEVEL-SYNCHRONOUS greedy NMS (R14, verified). Diag words from dwbuf.
__global__ void __launch_bounds__(64, 1) k_scan_fast(
    const u64* __restrict__ dwbuf, const u64* __restrict__ validw,
    const float4* __restrict__ boxes, float4* __restrict__ out,
    u32* __restrict__ okf, const u32* __restrict__ ecnt,
    const u32* __restrict__ edges) {
  __shared__ u64 dw[CW * 64];                // diag blocks
  __shared__ u64 al[CW], fw[CW], kp[CW], blkX[CW], supX[CW];
  __shared__ u32 eb[ECAP];                   // edge list
  __shared__ unsigned short list[KOUT];
  int l = threadIdx.x;
  int img = blockIdx.x;
  for (int c = 0; c < CW; c++)
    dw[c * 64 + l] = dwbuf[((size_t)img * CW + c) * 64 + l];
  u32 E = ecnt[img];
  if (E > (u32)ECAP) { if (l == 0) okf[img] = 0u; return; }
  for (u32 p = l; p < E; p += 64) eb[p] = edges[(size_t)img * ECAP + p];
  if (l < CW) {
    al[l] = validw[img * 96 + l];
    kp[l] = 0ull; blkX[l] = 0ull; supX[l] = 0ull;
  }
  __syncthreads();
  u64 lmask = (1ull << l) - 1ull;            // earlier-in-chunk rows
  bool fail = false;
  for (int round = 0; ; round++) {
    u64 anyv = (l < CW) ? al[l] : 0ull;
#pragma unroll
    for (int off = 32; off >= 1; off >>= 1) anyv |= __shfl_xor(anyv, off);
    if (anyv == 0ull) break;                 // all rows decided
    if (round >= RMAX) { fail = true; break; }
    for (u32 p = l; p < E; p += 64) {
      u32 e = eb[p];
      u32 tgt = e >> 16, src = e & 0xFFFFu;
      if ((al[src >> 6] >> (src & 63u)) & 1ull)
        atomicOr(&blkX[tgt >> 6], 1ull << (tgt & 63u));
    }
    for (int c = 0; c < CW; c++) {
      u64 a_c = al[c];
      u64 dj = dw[c * 64 + l];
      u64 blkin = __ballot((dj & a_c & lmask) != 0ull);
      if (l == 0) fw[c] = a_c & ~blkin & ~blkX[c];
    }
    for (u32 p = l; p < E; p += 64) {
      u32 e = eb[p];
      u32 tgt = e >> 16, src = e & 0xFFFFu;
      if ((fw[src >> 6] >> (src & 63u)) & 1ull)
        atomicOr(&supX[tgt >> 6], 1ull << (tgt & 63u));
    }
    for (int c = 0; c < CW; c++) {
      u64 f_c = fw[c];
      u64 dj = dw[c * 64 + l];
      u64 supin = __ballot((dj & f_c & lmask) != 0ull);
      if (l == 0) {
        kp[c] |= f_c;
        al[c] = al[c] & ~f_c & ~supin & ~supX[c];
      }
    }
    if (l < CW) { blkX[l] = 0ull; supX[l] = 0ull; }
  }
  u64 kw_l = (!fail && l < CW) ? kp[l] : 0ull;
  u32 pc = (u32)__popcll(kw_l);
  u32 pre = pc;
  for (int off = 1; off < 64; off <<= 1) {
    u32 v2 = __shfl_up(pre, off);
    if (l >= off) pre += v2;
  }
  u32 tot = __shfl(pre, 63);
  bool ok = !fail && (tot >= (u32)KOUT);
  if (l == 0) okf[img] = ok ? 1u : 0u;
  if (!ok) return;                           // rescue path takes over
  if (l < CW) {
    u32 b = pre - pc;
    u64 word = kw_l;
    while (word && b < (u32)KOUT) {
      int j = (int)__ffsll(word) - 1;
      word &= word - 1;
      list[b++] = (unsigned short)(l * 64 + j);
    }
  }
  __syncthreads();
  for (int p = l; p < KOUT; p += 64)
    out[(size_t)img * KOUT + p] = boxes[(size_t)img * 6016 + list[p]];
}

// K6b: full-depth rescue scan. No-op when fast scan succeeded.
__global__ void k_scan_full(const u64* __restrict__ mask, const u64* __restrict__ validw,
                            const float4* __restrict__ boxes, float4* __restrict__ out,
                            const u32* __restrict__ okf) {
  int img = blockIdx.x;
  if (okf[img]) return;
  __shared__ unsigned short kept[KOUT];
  int l = threadIdx.x;
  const u64* vw = validw + img * 96;
  u64 r0 = ~vw[l];
  u64 r1 = (l < MW - 64) ? ~vw[64 + l] : ~0ull;
  const u64* c0p = mask + ((size_t)img * 94 + l) * 6000;
  const u64* c1p = mask + ((size_t)img * 94 + (l < MW - 64 ? 64 + l : 0)) * 6000;

  u64 ca[16], cb[16], na[16], nb2[16];
#pragma unroll
  for (int k = 0; k < 16; k++) {
    ca[k] = c0p[k];
    cb[k] = (l < MW - 64) ? c1p[k] : 0ull;
  }
  int cnt = 0; bool done = false;
  for (int base = 0; base < PRE; base += 16) {
#pragma unroll
    for (int k = 0; k < 16; k++) {
      int rr = base + 16 + k;
      if (rr < PRE) {
        na[k]  = c0p[rr];
        nb2[k] = (l < MW - 64) ? c1p[rr] : 0ull;
      } else { na[k] = 0ull; nb2[k] = 0ull; }
    }
#pragma unroll
    for (int k = 0; k < 16; k++) {
      if (!done) {
        int i = base + k;
        int w = i >> 6;
        u64 wv = (w < 64) ? __shfl(r0, w) : __shfl(r1, w - 64);
        if (!((wv >> (i & 63)) & 1ull)) {
          if (l == 0 && cnt < KOUT) kept[cnt] = (unsigned short)i;
          cnt++;
          r0 |= (l >= w)        ? ca[k] : 0ull;
          r1 |= ((64 + l) >= w) ? cb[k] : 0ull;
          if (cnt >= KOUT) done = true;
        }
      }
    }
    if (done) break;
#pragma unroll
    for (int k = 0; k < 16; k++) { ca[k] = na[k]; cb[k] = nb2[k]; }
  }
  __syncthreads();
  for (int p = l; p < KOUT; p += 64) {
    float4 v = make_float4(0.f, 0.f, 0.f, 0.f);
    if (p < cnt) v = boxes[(size_t)img * 6016 + kept[p]];
    out[(size_t)img * KOUT + p] = v;
  }
}

extern "C" void kernel_launch(void* const* d_in, const int* in_sizes, int n_in,
                              void* d_out, int out_size, void* d_ws, size_t ws_size,
                              hipStream_t stream) {
  const float4* anch  = (const float4*)d_in[0];
  const float2* probs = (const float2*)d_in[1];
  const float4* delt  = (const float4*)d_in[2];
  float4* out = (float4*)d_out;
  char* ws = (char*)d_ws;
  (void)in_sizes; (void)n_in;

  if (ws_size < WS_NEED) {  // not enough scratch: write zeros, bail cleanly
    (void)hipMemsetAsync(d_out, 0, (size_t)out_size * sizeof(float), stream);
    return;
  }

  u64* mask    = (u64*)(ws + OFF_MASK);
  u64* sel     = (u64*)(ws + OFF_SEL);
  float4* bxs  = (float4*)(ws + OFF_BOX);
  u64* validw  = (u64*)(ws + OFF_VAL);
  u32* hist    = (u32*)(ws + OFF_HIST);
  u32* cab     = (u32*)(ws + OFF_CAB);
  u32* bincnt  = (u32*)(ws + OFF_BCNT);
  int* Tarr    = (int*)(ws + OFF_T);
  u32* Marr    = (u32*)(ws + OFF_M);
  u32* okf     = (u32*)(ws + OFF_FLAG);
  u32* ecnt    = (u32*)(ws + OFF_ECNT);
  u32* edges   = (u32*)(ws + OFF_EDG);
  u64* dwbuf   = (u64*)(ws + OFF_DW);
  u64* plist   = (u64*)(ws + OFF_PL);
  u32* pcnt    = (u32*)(ws + OFF_PCNT);

  k_zero<<<100, 256, 0, stream>>>((uint4*)(ws + OFF_VAL), (uint4*)(ws + OFF_PCNT));

  dim3 g1h(128, B);
  k_hist<<<g1h, 256, 0, stream>>>(anch, probs, delt, hist, bxs, plist, pcnt);
  k_thresh<<<B, 64, 0, stream>>>(hist, Tarr, cab, Marr);
  dim3 g1(256, B);
  k_hist_fb<<<g1, 256, 0, stream>>>(anch, probs, delt, Tarr, hist);
  k_thresh_fb<<<B, 64, 0, stream>>>(hist, Tarr, cab, Marr);
  dim3 g3(8, B);
  k_compact_fast<<<g3, 256, 0, stream>>>(plist, pcnt, Tarr, cab, bincnt, sel);
  dim3 g3b(32, B);
  k_compact_fb<<<g3b, 256, 0, stream>>>(anch, probs, delt, pcnt, Tarr, cab, bincnt, sel);
  dim3 g4(64, B);
  k_rank<<<g4, 256, 0, stream>>>(sel, cab, hist, Marr, anch, delt, bxs, validw);
  dim3 g5(NTILE, B);
  k_mask<<<g5, 256, 0, stream>>>(bxs, dwbuf, ecnt, edges);
  k_scan_fast<<<B, 64, 0, stream>>>(dwbuf, validw, bxs, out, okf, ecnt, edges);
  dim3 g5b(94, B);
  k_mask_rest<<<g5b, 256, 0, stream>>>(bxs, mask, okf);
  k_scan_full<<<B, 64, 0, stream>>>(mask, validw, bxs, out, okf);
}